// Round 1
// baseline (1927.955 us; speedup 1.0000x reference)
//
#include <hip/hip_runtime.h>

#define LOG2E 1.44269504088896340736f
#define TOPK 409

// ---------------------------------------------------------------------------
// QKV GEMM: X[8192,768] @ W[768,2304] + b, scattered to Q/K/V [B,H,S,D] fp32
// 128x128 tile, BK=16, 256 threads, 8x8 acc per thread (split 4+4 rows/cols).
// ---------------------------------------------------------------------------
__global__ __launch_bounds__(256) void qkv_gemm_kernel(
    const float* __restrict__ X, const float* __restrict__ W,
    const float* __restrict__ bias,
    float* __restrict__ Qo, float* __restrict__ Ko, float* __restrict__ Vo)
{
    __shared__ float As[16][128];  // As[k][m] (transposed for contiguous m)
    __shared__ float Bs[16][128];
    const int tid = threadIdx.x;
    const int m0 = blockIdx.y * 128;
    const int n0 = blockIdx.x * 128;
    const int tx = tid & 15, ty = tid >> 4;

    float acc[8][8];
#pragma unroll
    for (int i = 0; i < 8; ++i)
#pragma unroll
        for (int j = 0; j < 8; ++j) acc[i][j] = 0.f;

    const int arow = tid >> 1;           // 0..127
    const int aseg = (tid & 1) * 4;      // 0 / 4 (plus +8 second half)
    const int brow = tid >> 5;           // 0..7 (plus +8)
    const int bcol = (tid & 31) * 4;

    const float* Xp = X + (size_t)(m0 + arow) * 768;
    for (int k0 = 0; k0 < 768; k0 += 16) {
        float4 av0 = *(const float4*)&Xp[k0 + aseg];
        float4 av1 = *(const float4*)&Xp[k0 + aseg + 8];
        float4 bv0 = *(const float4*)&W[(size_t)(k0 + brow) * 2304 + n0 + bcol];
        float4 bv1 = *(const float4*)&W[(size_t)(k0 + brow + 8) * 2304 + n0 + bcol];
        __syncthreads();
        As[aseg + 0][arow] = av0.x; As[aseg + 1][arow] = av0.y;
        As[aseg + 2][arow] = av0.z; As[aseg + 3][arow] = av0.w;
        As[aseg + 8][arow] = av1.x; As[aseg + 9][arow] = av1.y;
        As[aseg + 10][arow] = av1.z; As[aseg + 11][arow] = av1.w;
        *(float4*)&Bs[brow][bcol] = bv0;
        *(float4*)&Bs[brow + 8][bcol] = bv1;
        __syncthreads();
#pragma unroll
        for (int kk = 0; kk < 16; ++kk) {
            float4 a0 = *(const float4*)&As[kk][ty * 4];
            float4 a1 = *(const float4*)&As[kk][64 + ty * 4];
            float4 b0 = *(const float4*)&Bs[kk][tx * 4];
            float4 b1 = *(const float4*)&Bs[kk][64 + tx * 4];
            float am[8] = {a0.x, a0.y, a0.z, a0.w, a1.x, a1.y, a1.z, a1.w};
            float bn[8] = {b0.x, b0.y, b0.z, b0.w, b1.x, b1.y, b1.z, b1.w};
#pragma unroll
            for (int i = 0; i < 8; ++i)
#pragma unroll
                for (int j = 0; j < 8; ++j) acc[i][j] += am[i] * bn[j];
        }
    }

    // epilogue: c -> (which, h, d); write float4 into Q/K/V [B,H,S,D]
#pragma unroll
    for (int i = 0; i < 8; ++i) {
        int r = m0 + ((i < 4) ? (ty * 4 + i) : (64 + ty * 4 + (i - 4)));
        int b = r >> 10, s = r & 1023;
#pragma unroll
        for (int half = 0; half < 2; ++half) {
            int c = n0 + half * 64 + tx * 4;
            int which = c / 768;
            int rem = c - which * 768;
            int h = rem >> 6, d = rem & 63;
            float* dst = (which == 0) ? Qo : (which == 1) ? Ko : Vo;
            float4 val;
            val.x = acc[i][half * 4 + 0] + bias[c + 0];
            val.y = acc[i][half * 4 + 1] + bias[c + 1];
            val.z = acc[i][half * 4 + 2] + bias[c + 2];
            val.w = acc[i][half * 4 + 3] + bias[c + 3];
            size_t idx = (((size_t)(b * 12 + h) * 1024 + s) * 64) + d;
            *(float4*)&dst[idx] = val;
        }
    }
}

// ---------------------------------------------------------------------------
// Proj GEMM: A[8192,768] @ W[768,768] + b -> out [8192,768]
// ---------------------------------------------------------------------------
__global__ __launch_bounds__(256) void proj_gemm_kernel(
    const float* __restrict__ X, const float* __restrict__ W,
    const float* __restrict__ bias, float* __restrict__ OUT)
{
    __shared__ float As[16][128];
    __shared__ float Bs[16][128];
    const int tid = threadIdx.x;
    const int m0 = blockIdx.y * 128;
    const int n0 = blockIdx.x * 128;
    const int tx = tid & 15, ty = tid >> 4;

    float acc[8][8];
#pragma unroll
    for (int i = 0; i < 8; ++i)
#pragma unroll
        for (int j = 0; j < 8; ++j) acc[i][j] = 0.f;

    const int arow = tid >> 1;
    const int aseg = (tid & 1) * 4;
    const int brow = tid >> 5;
    const int bcol = (tid & 31) * 4;

    const float* Xp = X + (size_t)(m0 + arow) * 768;
    for (int k0 = 0; k0 < 768; k0 += 16) {
        float4 av0 = *(const float4*)&Xp[k0 + aseg];
        float4 av1 = *(const float4*)&Xp[k0 + aseg + 8];
        float4 bv0 = *(const float4*)&W[(size_t)(k0 + brow) * 768 + n0 + bcol];
        float4 bv1 = *(const float4*)&W[(size_t)(k0 + brow + 8) * 768 + n0 + bcol];
        __syncthreads();
        As[aseg + 0][arow] = av0.x; As[aseg + 1][arow] = av0.y;
        As[aseg + 2][arow] = av0.z; As[aseg + 3][arow] = av0.w;
        As[aseg + 8][arow] = av1.x; As[aseg + 9][arow] = av1.y;
        As[aseg + 10][arow] = av1.z; As[aseg + 11][arow] = av1.w;
        *(float4*)&Bs[brow][bcol] = bv0;
        *(float4*)&Bs[brow + 8][bcol] = bv1;
        __syncthreads();
#pragma unroll
        for (int kk = 0; kk < 16; ++kk) {
            float4 a0 = *(const float4*)&As[kk][ty * 4];
            float4 a1 = *(const float4*)&As[kk][64 + ty * 4];
            float4 b0 = *(const float4*)&Bs[kk][tx * 4];
            float4 b1 = *(const float4*)&Bs[kk][64 + tx * 4];
            float am[8] = {a0.x, a0.y, a0.z, a0.w, a1.x, a1.y, a1.z, a1.w};
            float bn[8] = {b0.x, b0.y, b0.z, b0.w, b1.x, b1.y, b1.z, b1.w};
#pragma unroll
            for (int i = 0; i < 8; ++i)
#pragma unroll
                for (int j = 0; j < 8; ++j) acc[i][j] += am[i] * bn[j];
        }
    }

#pragma unroll
    for (int i = 0; i < 8; ++i) {
        int r = m0 + ((i < 4) ? (ty * 4 + i) : (64 + ty * 4 + (i - 4)));
#pragma unroll
        for (int half = 0; half < 2; ++half) {
            int c = n0 + half * 64 + tx * 4;
            float4 val;
            val.x = acc[i][half * 4 + 0] + bias[c + 0];
            val.y = acc[i][half * 4 + 1] + bias[c + 1];
            val.z = acc[i][half * 4 + 2] + bias[c + 2];
            val.w = acc[i][half * 4 + 3] + bias[c + 3];
            *(float4*)&OUT[(size_t)r * 768 + c] = val;
        }
    }
}

// ---------------------------------------------------------------------------
// Fused attention: per block = (head, 8-row q tile).
// scores (fp32, LDS) -> exact top-k (binary search on sortable uints) ->
// masked softmax (in-place) -> P @ V (V read direct from global, coalesced).
// ---------------------------------------------------------------------------
__global__ __launch_bounds__(256) void attn_kernel(
    const float* __restrict__ Qg, const float* __restrict__ Kg,
    const float* __restrict__ Vg, float* __restrict__ O)
{
    const int head = blockIdx.y;   // b*12 + h
    const int qt = blockIdx.x;     // 0..127
    const int b = head / 12, h = head - b * 12;
    const float* Qp = Qg + ((size_t)head * 1024 + qt * 8) * 64;
    const float* Kp = Kg + (size_t)head * 1024 * 64;
    const float* Vp = Vg + (size_t)head * 1024 * 64;

    __shared__ float S_lds[8][1024];   // scores, then P (32 KB)
    __shared__ float Q_lds[8][64];     // 2 KB
    __shared__ float K_lds[64][65];    // padded: (j + d) % 32 banks, 2-way free
    __shared__ float rsum[8];

    const int tid = threadIdx.x;

    // load Q tile (8x64) with threads 0..127
    if (tid < 128) {
        int r = tid >> 4, c = (tid & 15) * 4;
        *(float4*)&Q_lds[r][c] = *(const float4*)&Qp[r * 64 + c];
    }

    const int j = tid & 63;    // score column within K tile
    const int r0 = tid >> 6;   // 0..3
    const int r1 = r0 + 4;

    const int kr = tid >> 2;          // K row to stage
    const int kc = (tid & 3) * 16;    // 16-float segment

    // ---- Phase 1: scores S = (Q K^T) * scale, into LDS ----
    for (int t = 0; t < 16; ++t) {
        const float* Kt = Kp + (size_t)(t * 64) * 64;
        float4 kv[4];
#pragma unroll
        for (int i = 0; i < 4; ++i) kv[i] = *(const float4*)&Kt[kr * 64 + kc + i * 4];
        __syncthreads();   // previous tile's readers done (t=0: Q_lds visible)
#pragma unroll
        for (int i = 0; i < 4; ++i) {
            K_lds[kr][kc + i * 4 + 0] = kv[i].x;
            K_lds[kr][kc + i * 4 + 1] = kv[i].y;
            K_lds[kr][kc + i * 4 + 2] = kv[i].z;
            K_lds[kr][kc + i * 4 + 3] = kv[i].w;
        }
        __syncthreads();
        float s0 = 0.f, s1 = 0.f;
#pragma unroll
        for (int d = 0; d < 64; d += 4) {
            float4 q0 = *(const float4*)&Q_lds[r0][d];   // broadcast
            float4 q1 = *(const float4*)&Q_lds[r1][d];   // broadcast
            float k0v = K_lds[j][d + 0];
            float k1v = K_lds[j][d + 1];
            float k2v = K_lds[j][d + 2];
            float k3v = K_lds[j][d + 3];
            s0 += q0.x * k0v + q0.y * k1v + q0.z * k2v + q0.w * k3v;
            s1 += q1.x * k0v + q1.y * k1v + q1.z * k2v + q1.w * k3v;
        }
        S_lds[r0][t * 64 + j] = s0 * 0.125f;
        S_lds[r1][t * 64 + j] = s1 * 0.125f;
    }
    __syncthreads();

    // ---- Phase 2: per-row exact top-k + masked softmax (wave w -> rows 2w,2w+1)
    {
        const int lane = tid & 63;
        const int w = tid >> 6;
        const int ra = 2 * w, rb = 2 * w + 1;
        float fa[16], fb[16];
        unsigned ua[16], ub[16];
#pragma unroll
        for (int i = 0; i < 16; ++i) {
            fa[i] = S_lds[ra][lane + 64 * i];
            fb[i] = S_lds[rb][lane + 64 * i];
        }
        float ma = fa[0], mb = fb[0];
#pragma unroll
        for (int i = 1; i < 16; ++i) { ma = fmaxf(ma, fa[i]); mb = fmaxf(mb, fb[i]); }
        for (int off = 32; off; off >>= 1) {
            ma = fmaxf(ma, __shfl_xor(ma, off));
            mb = fmaxf(mb, __shfl_xor(mb, off));
        }
#pragma unroll
        for (int i = 0; i < 16; ++i) {
            unsigned u = __float_as_uint(fa[i]);
            ua[i] = (u & 0x80000000u) ? ~u : (u | 0x80000000u);
            u = __float_as_uint(fb[i]);
            ub[i] = (u & 0x80000000u) ? ~u : (u | 0x80000000u);
        }
        // binary search for k-th largest (max u with count(>=u) >= TOPK)
        unsigned ansa = 0u, ansb = 0u;
        for (int bit = 31; bit >= 0; --bit) {
            unsigned ca = ansa | (1u << bit);
            unsigned cb = ansb | (1u << bit);
            int cnt = 0;
#pragma unroll
            for (int i = 0; i < 16; ++i) {
                cnt += (ua[i] >= ca) ? 1 : 0;
                cnt += (ub[i] >= cb) ? 0x10000 : 0;
            }
            for (int off = 32; off; off >>= 1) cnt += __shfl_xor(cnt, off);
            if ((cnt & 0xffff) >= TOPK) ansa = ca;
            if ((cnt >> 16) >= TOPK) ansb = cb;
        }
        // masked exp, in-place into S_lds; row sums
        float sa = 0.f, sb = 0.f;
#pragma unroll
        for (int i = 0; i < 16; ++i) {
            float ea = (ua[i] >= ansa) ? exp2f((fa[i] - ma) * LOG2E) : 0.f;
            float eb = (ub[i] >= ansb) ? exp2f((fb[i] - mb) * LOG2E) : 0.f;
            S_lds[ra][lane + 64 * i] = ea;
            S_lds[rb][lane + 64 * i] = eb;
            sa += ea; sb += eb;
        }
        for (int off = 32; off; off >>= 1) {
            sa += __shfl_xor(sa, off);
            sb += __shfl_xor(sb, off);
        }
        if (lane == 0) { rsum[ra] = sa; rsum[rb] = sb; }
    }
    __syncthreads();

    // ---- Phase 3: O = P @ V ; V direct from global (lane = d -> coalesced) ----
    {
        const int d = tid & 63;
        float o0 = 0.f, o1 = 0.f;
        for (int jj = 0; jj < 1024; jj += 4) {
            float4 p0 = *(const float4*)&S_lds[r0][jj];   // broadcast
            float4 p1 = *(const float4*)&S_lds[r1][jj];   // broadcast
            float v0 = Vp[(size_t)(jj + 0) * 64 + d];
            float v1 = Vp[(size_t)(jj + 1) * 64 + d];
            float v2 = Vp[(size_t)(jj + 2) * 64 + d];
            float v3 = Vp[(size_t)(jj + 3) * 64 + d];
            o0 += p0.x * v0 + p0.y * v1 + p0.z * v2 + p0.w * v3;
            o1 += p1.x * v0 + p1.y * v1 + p1.z * v2 + p1.w * v3;
        }
        int s0r = qt * 8 + r0, s1r = qt * 8 + r1;
        O[((size_t)(b * 1024 + s0r)) * 768 + h * 64 + d] = o0 * (1.f / rsum[r0]);
        O[((size_t)(b * 1024 + s1r)) * 768 + h * 64 + d] = o1 * (1.f / rsum[r1]);
    }
}

extern "C" void kernel_launch(void* const* d_in, const int* in_sizes, int n_in,
                              void* d_out, int out_size, void* d_ws, size_t ws_size,
                              hipStream_t stream)
{
    const float* X     = (const float*)d_in[0];  // [8,1024,768]
    const float* Wqkv  = (const float*)d_in[1];  // [768,2304]
    const float* bqkv  = (const float*)d_in[2];  // [2304]
    const float* Wproj = (const float*)d_in[3];  // [768,768]
    const float* bproj = (const float*)d_in[4];  // [768]
    float* out = (float*)d_out;                  // [8,1024,768] fp32
    float* ws = (float*)d_ws;

    const size_t per = (size_t)96 * 1024 * 64;   // 6291456 floats
    float* Qb = ws;
    float* Kb = ws + per;
    float* Vb = ws + 2 * per;
    float* Ao = ws + 3 * per;                    // attention output [B,S,E]

    qkv_gemm_kernel<<<dim3(18, 64), 256, 0, stream>>>(X, Wqkv, bqkv, Qb, Kb, Vb);
    attn_kernel<<<dim3(128, 96), 256, 0, stream>>>(Qb, Kb, Vb, Ao);
    proj_gemm_kernel<<<dim3(6, 64), 256, 0, stream>>>(Ao, Wproj, bproj, out);
}

// Round 2
// 1036.166 us; speedup vs baseline: 1.8607x; 1.8607x over previous
//
#include <hip/hip_runtime.h>

#define LOG2E 1.44269504088896340736f
#define TOPK 409

typedef __attribute__((ext_vector_type(8))) short bf16x8;
typedef __attribute__((ext_vector_type(4))) float f32x4;
typedef __attribute__((ext_vector_type(4))) unsigned short us4;

__device__ __forceinline__ unsigned short f2bf(float f) {
    unsigned u = __float_as_uint(f);
    unsigned r = (u + 0x7fffu + ((u >> 16) & 1u)) >> 16;   // RNE
    return (unsigned short)r;
}
__device__ __forceinline__ float bf2f(unsigned short h) {
    return __uint_as_float(((unsigned)h) << 16);
}

// ---------------------------------------------------------------------------
// QKV GEMM: X[8192,768] @ W[768,2304] + b  ->  Qhi/Qlo/Khi/Klo [H,S,64] bf16,
// Vt [H,64,1024] bf16 (transposed for PV MFMA B-fragments).
// ---------------------------------------------------------------------------
__global__ __launch_bounds__(256) void qkv_gemm_kernel(
    const float* __restrict__ X, const float* __restrict__ W,
    const float* __restrict__ bias,
    unsigned short* __restrict__ Qhi, unsigned short* __restrict__ Qlo,
    unsigned short* __restrict__ Khi, unsigned short* __restrict__ Klo,
    unsigned short* __restrict__ Vt)
{
    __shared__ float As[16][128];  // As[k][m]
    __shared__ float Bs[16][128];
    const int tid = threadIdx.x;
    const int m0 = blockIdx.y * 128;
    const int n0 = blockIdx.x * 128;
    const int tx = tid & 15, ty = tid >> 4;

    float acc[8][8];
#pragma unroll
    for (int i = 0; i < 8; ++i)
#pragma unroll
        for (int j = 0; j < 8; ++j) acc[i][j] = 0.f;

    const int arow = tid >> 1;
    const int aseg = (tid & 1) * 4;
    const int brow = tid >> 5;
    const int bcol = (tid & 31) * 4;

    const float* Xp = X + (size_t)(m0 + arow) * 768;
    for (int k0 = 0; k0 < 768; k0 += 16) {
        float4 av0 = *(const float4*)&Xp[k0 + aseg];
        float4 av1 = *(const float4*)&Xp[k0 + aseg + 8];
        float4 bv0 = *(const float4*)&W[(size_t)(k0 + brow) * 2304 + n0 + bcol];
        float4 bv1 = *(const float4*)&W[(size_t)(k0 + brow + 8) * 2304 + n0 + bcol];
        __syncthreads();
        As[aseg + 0][arow] = av0.x; As[aseg + 1][arow] = av0.y;
        As[aseg + 2][arow] = av0.z; As[aseg + 3][arow] = av0.w;
        As[aseg + 8][arow] = av1.x; As[aseg + 9][arow] = av1.y;
        As[aseg + 10][arow] = av1.z; As[aseg + 11][arow] = av1.w;
        *(float4*)&Bs[brow][bcol] = bv0;
        *(float4*)&Bs[brow + 8][bcol] = bv1;
        __syncthreads();
#pragma unroll
        for (int kk = 0; kk < 16; ++kk) {
            float4 a0 = *(const float4*)&As[kk][ty * 4];
            float4 a1 = *(const float4*)&As[kk][64 + ty * 4];
            float4 b0 = *(const float4*)&Bs[kk][tx * 4];
            float4 b1 = *(const float4*)&Bs[kk][64 + tx * 4];
            float am[8] = {a0.x, a0.y, a0.z, a0.w, a1.x, a1.y, a1.z, a1.w};
            float bn[8] = {b0.x, b0.y, b0.z, b0.w, b1.x, b1.y, b1.z, b1.w};
#pragma unroll
            for (int i = 0; i < 8; ++i)
#pragma unroll
                for (int j = 0; j < 8; ++j) acc[i][j] += am[i] * bn[j];
        }
    }

#pragma unroll
    for (int i = 0; i < 8; ++i) {
        int r = m0 + ((i < 4) ? (ty * 4 + i) : (64 + ty * 4 + (i - 4)));
        int bb = r >> 10, s = r & 1023;
#pragma unroll
        for (int half = 0; half < 2; ++half) {
            int c = n0 + half * 64 + tx * 4;
            int which = c / 768;
            int rem = c - which * 768;
            int h = rem >> 6, d = rem & 63;
            int head = bb * 12 + h;
            float v[4];
#pragma unroll
            for (int k = 0; k < 4; ++k) v[k] = acc[i][half * 4 + k] + bias[c + k];
            if (which == 2) {
                // Vt[head][d+k][s]
#pragma unroll
                for (int k = 0; k < 4; ++k)
                    Vt[(size_t)head * 65536 + (size_t)(d + k) * 1024 + s] = f2bf(v[k]);
            } else {
                us4 hi4, lo4;
#pragma unroll
                for (int k = 0; k < 4; ++k) {
                    unsigned short hb = f2bf(v[k]);
                    hi4[k] = hb;
                    lo4[k] = f2bf(v[k] - bf2f(hb));
                }
                unsigned short* HP = which ? Khi : Qhi;
                unsigned short* LP = which ? Klo : Qlo;
                size_t idx = (size_t)head * 65536 + (size_t)s * 64 + d;
                *(us4*)&HP[idx] = hi4;
                *(us4*)&LP[idx] = lo4;
            }
        }
    }
}

// ---------------------------------------------------------------------------
// Proj GEMM: A[8192,768] @ W[768,768] + b -> out (fp32)
// ---------------------------------------------------------------------------
__global__ __launch_bounds__(256) void proj_gemm_kernel(
    const float* __restrict__ X, const float* __restrict__ W,
    const float* __restrict__ bias, float* __restrict__ OUT)
{
    __shared__ float As[16][128];
    __shared__ float Bs[16][128];
    const int tid = threadIdx.x;
    const int m0 = blockIdx.y * 128;
    const int n0 = blockIdx.x * 128;
    const int tx = tid & 15, ty = tid >> 4;

    float acc[8][8];
#pragma unroll
    for (int i = 0; i < 8; ++i)
#pragma unroll
        for (int j = 0; j < 8; ++j) acc[i][j] = 0.f;

    const int arow = tid >> 1;
    const int aseg = (tid & 1) * 4;
    const int brow = tid >> 5;
    const int bcol = (tid & 31) * 4;

    const float* Xp = X + (size_t)(m0 + arow) * 768;
    for (int k0 = 0; k0 < 768; k0 += 16) {
        float4 av0 = *(const float4*)&Xp[k0 + aseg];
        float4 av1 = *(const float4*)&Xp[k0 + aseg + 8];
        float4 bv0 = *(const float4*)&W[(size_t)(k0 + brow) * 768 + n0 + bcol];
        float4 bv1 = *(const float4*)&W[(size_t)(k0 + brow + 8) * 768 + n0 + bcol];
        __syncthreads();
        As[aseg + 0][arow] = av0.x; As[aseg + 1][arow] = av0.y;
        As[aseg + 2][arow] = av0.z; As[aseg + 3][arow] = av0.w;
        As[aseg + 8][arow] = av1.x; As[aseg + 9][arow] = av1.y;
        As[aseg + 10][arow] = av1.z; As[aseg + 11][arow] = av1.w;
        *(float4*)&Bs[brow][bcol] = bv0;
        *(float4*)&Bs[brow + 8][bcol] = bv1;
        __syncthreads();
#pragma unroll
        for (int kk = 0; kk < 16; ++kk) {
            float4 a0 = *(const float4*)&As[kk][ty * 4];
            float4 a1 = *(const float4*)&As[kk][64 + ty * 4];
            float4 b0 = *(const float4*)&Bs[kk][tx * 4];
            float4 b1 = *(const float4*)&Bs[kk][64 + tx * 4];
            float am[8] = {a0.x, a0.y, a0.z, a0.w, a1.x, a1.y, a1.z, a1.w};
            float bn[8] = {b0.x, b0.y, b0.z, b0.w, b1.x, b1.y, b1.z, b1.w};
#pragma unroll
            for (int i = 0; i < 8; ++i)
#pragma unroll
                for (int j = 0; j < 8; ++j) acc[i][j] += am[i] * bn[j];
        }
    }

#pragma unroll
    for (int i = 0; i < 8; ++i) {
        int r = m0 + ((i < 4) ? (ty * 4 + i) : (64 + ty * 4 + (i - 4)));
#pragma unroll
        for (int half = 0; half < 2; ++half) {
            int c = n0 + half * 64 + tx * 4;
            float4 val;
            val.x = acc[i][half * 4 + 0] + bias[c + 0];
            val.y = acc[i][half * 4 + 1] + bias[c + 1];
            val.z = acc[i][half * 4 + 2] + bias[c + 2];
            val.w = acc[i][half * 4 + 3] + bias[c + 3];
            *(float4*)&OUT[(size_t)r * 768 + c] = val;
        }
    }
}

// ---------------------------------------------------------------------------
// Attention: block = (16 q-rows, head). 4 waves.
//   Phase 1: S = (Qhi·Khi + Qhi·Klo + Qlo·Khi)*scale via MFMA -> LDS (64 KB)
//   Phase 2: exact top-k (binary search on sortable uints, 1 row / 16 lanes)
//            + masked exp, in place
//   Phase 3: O = P·V via bf16 MFMA (Vt fragments from global), cross-wave
//            reduce through LDS, scale by 1/rowsum, store fp32.
// ---------------------------------------------------------------------------
__global__ __launch_bounds__(256) void attn_kernel(
    const unsigned short* __restrict__ Qhi, const unsigned short* __restrict__ Qlo,
    const unsigned short* __restrict__ Khi, const unsigned short* __restrict__ Klo,
    const unsigned short* __restrict__ Vt, float* __restrict__ O)
{
    __shared__ float S[16 * 1024];   // 64 KB: scores -> P -> partials(+rsum)

    const int head = blockIdx.y;
    const int qt = blockIdx.x;       // 16-row q tile
    const int bb = head / 12, h = head - bb * 12;
    const int tid = threadIdx.x;
    const int w = tid >> 6, lane = tid & 63;
    const int l16 = lane & 15, quad = lane >> 4;

    const size_t hbase = (size_t)head * 65536;
    const unsigned short* Qhp = Qhi + hbase + (size_t)(qt * 16) * 64;
    const unsigned short* Qlp = Qlo + hbase + (size_t)(qt * 16) * 64;
    const unsigned short* Khp = Khi + hbase;
    const unsigned short* Klp = Klo + hbase;
    const unsigned short* Vp  = Vt + hbase;   // [64][1024]

    // Q fragments: A[m=l16][k=quad*8+j], k-chunks 0/1
    bf16x8 qh0, qh1, ql0, ql1;
    {
        int off = l16 * 64 + quad * 8;
        qh0 = *(const bf16x8*)(Qhp + off);
        qh1 = *(const bf16x8*)(Qhp + off + 32);
        ql0 = *(const bf16x8*)(Qlp + off);
        ql1 = *(const bf16x8*)(Qlp + off + 32);
    }

    // ---- Phase 1: scores for cols [w*256, w*256+256) ----
    for (int t = 0; t < 16; ++t) {
        int col0 = w * 256 + t * 16;
        int off = (col0 + l16) * 64 + quad * 8;
        bf16x8 kh0 = *(const bf16x8*)(Khp + off);
        bf16x8 kh1 = *(const bf16x8*)(Khp + off + 32);
        bf16x8 kl0 = *(const bf16x8*)(Klp + off);
        bf16x8 kl1 = *(const bf16x8*)(Klp + off + 32);
        f32x4 acc = {0.f, 0.f, 0.f, 0.f};
        acc = __builtin_amdgcn_mfma_f32_16x16x32_bf16(qh0, kh0, acc, 0, 0, 0);
        acc = __builtin_amdgcn_mfma_f32_16x16x32_bf16(qh1, kh1, acc, 0, 0, 0);
        acc = __builtin_amdgcn_mfma_f32_16x16x32_bf16(qh0, kl0, acc, 0, 0, 0);
        acc = __builtin_amdgcn_mfma_f32_16x16x32_bf16(qh1, kl1, acc, 0, 0, 0);
        acc = __builtin_amdgcn_mfma_f32_16x16x32_bf16(ql0, kh0, acc, 0, 0, 0);
        acc = __builtin_amdgcn_mfma_f32_16x16x32_bf16(ql1, kh1, acc, 0, 0, 0);
#pragma unroll
        for (int r = 0; r < 4; ++r)
            S[(quad * 4 + r) * 1024 + col0 + l16] = acc[r] * 0.125f;
    }
    __syncthreads();

    // ---- Phase 2: row r2 handled by 16-lane group; 64 values/lane ----
    const int r2 = w * 4 + quad;
    float* Srow = &S[r2 * 1024];
    unsigned ua[64];
    float m = -1e30f;
#pragma unroll
    for (int i = 0; i < 16; ++i) {
        f32x4 v = *(const f32x4*)&Srow[l16 * 4 + i * 64];
#pragma unroll
        for (int k = 0; k < 4; ++k) {
            float f = v[k];
            m = fmaxf(m, f);
            unsigned u = __float_as_uint(f);
            ua[i * 4 + k] = u ^ ((unsigned)((int)u >> 31) | 0x80000000u);
        }
    }
#pragma unroll
    for (int off = 8; off; off >>= 1) m = fmaxf(m, __shfl_xor(m, off));

    unsigned ans = 0u;
    for (int bit = 31; bit >= 0; --bit) {
        unsigned c = ans | (1u << bit);
        int cnt = 0;
#pragma unroll
        for (int i = 0; i < 64; ++i) cnt += (ua[i] >= c) ? 1 : 0;
        cnt += __shfl_xor(cnt, 1);
        cnt += __shfl_xor(cnt, 2);
        cnt += __shfl_xor(cnt, 4);
        cnt += __shfl_xor(cnt, 8);
        if (cnt >= TOPK) ans = c;
    }

    float ssum = 0.f;
#pragma unroll
    for (int i = 0; i < 64; ++i) {
        unsigned u = ua[i];
        unsigned fb = (u & 0x80000000u) ? (u & 0x7fffffffu) : ~u;
        float f = __uint_as_float(fb);
        float e = (u >= ans) ? exp2f((f - m) * LOG2E) : 0.f;
        ssum += e;
        Srow[l16 * 4 + (i >> 2) * 64 + (i & 3)] = e;
    }
#pragma unroll
    for (int off = 8; off; off >>= 1) ssum += __shfl_xor(ssum, off);
    const float rsum = ssum;   // valid in all lanes of the group
    __syncthreads();

    // ---- Phase 3: partial O over k in [w*256, w*256+256) ----
    f32x4 oacc[4];
#pragma unroll
    for (int nt = 0; nt < 4; ++nt) oacc[nt] = (f32x4){0.f, 0.f, 0.f, 0.f};

    for (int step = 0; step < 8; ++step) {
        int k0 = w * 256 + step * 32;
        f32x4 p0 = *(const f32x4*)&S[l16 * 1024 + k0 + quad * 8];
        f32x4 p1 = *(const f32x4*)&S[l16 * 1024 + k0 + quad * 8 + 4];
        bf16x8 a;
#pragma unroll
        for (int k = 0; k < 4; ++k) a[k] = (short)f2bf(p0[k]);
#pragma unroll
        for (int k = 0; k < 4; ++k) a[4 + k] = (short)f2bf(p1[k]);
#pragma unroll
        for (int nt = 0; nt < 4; ++nt) {
            bf16x8 bfrag = *(const bf16x8*)(Vp + (size_t)(nt * 16 + l16) * 1024 + k0 + quad * 8);
            oacc[nt] = __builtin_amdgcn_mfma_f32_16x16x32_bf16(a, bfrag, oacc[nt], 0, 0, 0);
        }
    }
    __syncthreads();   // all P reads done; S reusable

    // partials: S[(w*16 + row)*64 + col], rsum at S[4096 + r]
#pragma unroll
    for (int nt = 0; nt < 4; ++nt)
#pragma unroll
        for (int r = 0; r < 4; ++r)
            S[(w * 16 + quad * 4 + r) * 64 + nt * 16 + l16] = oacc[nt][r];
    if (l16 == 0) S[4096 + r2] = rsum;
    __syncthreads();

    {
        int row = tid >> 4, ds = (tid & 15) * 4;
        f32x4 o = {0.f, 0.f, 0.f, 0.f};
#pragma unroll
        for (int ww = 0; ww < 4; ++ww)
            o += *(const f32x4*)&S[(ww * 16 + row) * 64 + ds];
        float inv = 1.f / S[4096 + row];
        int srow = qt * 16 + row;
        float4 res;
        res.x = o[0] * inv; res.y = o[1] * inv; res.z = o[2] * inv; res.w = o[3] * inv;
        *(float4*)&O[((size_t)(bb * 1024 + srow)) * 768 + h * 64 + ds] = res;
    }
}

extern "C" void kernel_launch(void* const* d_in, const int* in_sizes, int n_in,
                              void* d_out, int out_size, void* d_ws, size_t ws_size,
                              hipStream_t stream)
{
    const float* X     = (const float*)d_in[0];
    const float* Wqkv  = (const float*)d_in[1];
    const float* bqkv  = (const float*)d_in[2];
    const float* Wproj = (const float*)d_in[3];
    const float* bproj = (const float*)d_in[4];
    float* out = (float*)d_out;

    unsigned short* us = (unsigned short*)d_ws;
    const size_t per = (size_t)96 * 1024 * 64;   // 6291456 elements
    unsigned short* Qhi = us;
    unsigned short* Qlo = us + per;
    unsigned short* Khi = us + 2 * per;
    unsigned short* Klo = us + 3 * per;
    unsigned short* Vt  = us + 4 * per;
    float* Ao = (float*)(us + 5 * per);          // [8,1024,768] fp32

    qkv_gemm_kernel<<<dim3(18, 64), 256, 0, stream>>>(X, Wqkv, bqkv, Qhi, Qlo, Khi, Klo, Vt);
    attn_kernel<<<dim3(64, 96), 256, 0, stream>>>(Qhi, Qlo, Khi, Klo, Vt, Ao);
    proj_gemm_kernel<<<dim3(6, 64), 256, 0, stream>>>(Ao, Wproj, bproj, out);
}

// Round 4
// 731.366 us; speedup vs baseline: 2.6361x; 1.4168x over previous
//
#include <hip/hip_runtime.h>

#define LOG2E 1.44269504088896340736f
#define TOPK 409

typedef __attribute__((ext_vector_type(8))) short bf16x8;
typedef __attribute__((ext_vector_type(4))) float f32x4;
typedef __attribute__((ext_vector_type(4))) unsigned short us4;

__device__ __forceinline__ unsigned short f2bf(float f) {
    unsigned u = __float_as_uint(f);
    unsigned r = (u + 0x7fffu + ((u >> 16) & 1u)) >> 16;   // RNE
    return (unsigned short)r;
}
__device__ __forceinline__ float bf2f(unsigned short h) {
    return __uint_as_float(((unsigned)h) << 16);
}

// ---------------------------------------------------------------------------
// Cast X fp32 -> Xhi/Xlo bf16 (grid covers 6291456 elements exactly)
// ---------------------------------------------------------------------------
__global__ __launch_bounds__(256) void cast_x_kernel(
    const float* __restrict__ X, unsigned short* __restrict__ Xhi,
    unsigned short* __restrict__ Xlo)
{
    int i = (blockIdx.x * 256 + threadIdx.x) * 8;
    float4 a = *(const float4*)&X[i];
    float4 b = *(const float4*)&X[i + 4];
    float v[8] = {a.x, a.y, a.z, a.w, b.x, b.y, b.z, b.w};
    us4 h0, h1, l0, l1;
#pragma unroll
    for (int k = 0; k < 4; ++k) {
        unsigned short hb = f2bf(v[k]);
        h0[k] = hb; l0[k] = f2bf(v[k] - bf2f(hb));
        unsigned short hb2 = f2bf(v[4 + k]);
        h1[k] = hb2; l1[k] = f2bf(v[4 + k] - bf2f(hb2));
    }
    *(us4*)&Xhi[i] = h0; *(us4*)&Xhi[i + 4] = h1;
    *(us4*)&Xlo[i] = l0; *(us4*)&Xlo[i + 4] = l1;
}

// ---------------------------------------------------------------------------
// W[K,N] fp32 -> Th/Tl[N,K] bf16 (transpose + hi/lo split), 32x32 LDS tiles
// ---------------------------------------------------------------------------
__global__ __launch_bounds__(256) void transpose_split_kernel(
    const float* __restrict__ W, unsigned short* __restrict__ Th,
    unsigned short* __restrict__ Tl, int K, int N)
{
    __shared__ float T[32][33];
    const int tx = threadIdx.x & 31, ty = threadIdx.x >> 5;   // ty 0..7
    const int n0 = blockIdx.x * 32, k0 = blockIdx.y * 32;
#pragma unroll
    for (int r = 0; r < 4; ++r)
        T[ty + r * 8][tx] = W[(size_t)(k0 + ty + r * 8) * N + n0 + tx];
    __syncthreads();
#pragma unroll
    for (int r = 0; r < 4; ++r) {
        int nl = ty + r * 8;
        float v = T[tx][nl];
        unsigned short hb = f2bf(v);
        Th[(size_t)(n0 + nl) * K + k0 + tx] = hb;
        Tl[(size_t)(n0 + nl) * K + k0 + tx] = f2bf(v - bf2f(hb));
    }
}

// ---------------------------------------------------------------------------
// QKV GEMM via MFMA: C = X @ Wqkv + b. A = Xhi/Xlo [8192,768] bf16,
// B = Wt hi/lo [2304,768] bf16 (row n contiguous in k). 128x128 tile, BK=32.
// Q/K n-blocks: 3-pass split (hi.hi + hi.lo + lo.hi); V block: 1-pass.
// Epilogue scatters to Qhi/Qlo/Khi/Klo [H,S,64] and Vt [H,64,1024].
// ---------------------------------------------------------------------------
__global__ __launch_bounds__(256) void qkv_mfma_kernel(
    const unsigned short* __restrict__ Xhi, const unsigned short* __restrict__ Xlo,
    const unsigned short* __restrict__ Bhg, const unsigned short* __restrict__ Blg,
    const float* __restrict__ bias,
    unsigned short* __restrict__ Qhi, unsigned short* __restrict__ Qlo,
    unsigned short* __restrict__ Khi, unsigned short* __restrict__ Klo,
    unsigned short* __restrict__ Vt)
{
    __shared__ unsigned short Ah[128 * 32], Al[128 * 32];
    __shared__ unsigned short Bh[128 * 32], Bl[128 * 32];
    const int tid = threadIdx.x;
    const int n0 = blockIdx.x * 128, m0 = blockIdx.y * 128;
    const int which = n0 / 768;               // block-uniform
    const bool threep = (which < 2);
    const int lane = tid & 63, l16 = lane & 15, quad = lane >> 4;
    const int w = tid >> 6, wm = w >> 1, wn = w & 1;

    f32x4 acc[4][4];
#pragma unroll
    for (int mi = 0; mi < 4; ++mi)
#pragma unroll
        for (int ni = 0; ni < 4; ++ni) acc[mi][ni] = (f32x4){0.f, 0.f, 0.f, 0.f};

    const int r0 = tid >> 2, kc = (tid & 3) * 8;   // staging: rows r0, r0+64
    const int r1 = r0 + 64;

    for (int k0 = 0; k0 < 768; k0 += 32) {
        bf16x8 ah0 = *(const bf16x8*)&Xhi[(size_t)(m0 + r0) * 768 + k0 + kc];
        bf16x8 ah1 = *(const bf16x8*)&Xhi[(size_t)(m0 + r1) * 768 + k0 + kc];
        bf16x8 bh0 = *(const bf16x8*)&Bhg[(size_t)(n0 + r0) * 768 + k0 + kc];
        bf16x8 bh1 = *(const bf16x8*)&Bhg[(size_t)(n0 + r1) * 768 + k0 + kc];
        bf16x8 al0 = {}, al1 = {}, bl0 = {}, bl1 = {};
        if (threep) {
            al0 = *(const bf16x8*)&Xlo[(size_t)(m0 + r0) * 768 + k0 + kc];
            al1 = *(const bf16x8*)&Xlo[(size_t)(m0 + r1) * 768 + k0 + kc];
            bl0 = *(const bf16x8*)&Blg[(size_t)(n0 + r0) * 768 + k0 + kc];
            bl1 = *(const bf16x8*)&Blg[(size_t)(n0 + r1) * 768 + k0 + kc];
        }
        __syncthreads();
        *(bf16x8*)&Ah[r0 * 32 + kc] = ah0;
        *(bf16x8*)&Ah[r1 * 32 + kc] = ah1;
        *(bf16x8*)&Bh[r0 * 32 + kc] = bh0;
        *(bf16x8*)&Bh[r1 * 32 + kc] = bh1;
        if (threep) {
            *(bf16x8*)&Al[r0 * 32 + kc] = al0;
            *(bf16x8*)&Al[r1 * 32 + kc] = al1;
            *(bf16x8*)&Bl[r0 * 32 + kc] = bl0;
            *(bf16x8*)&Bl[r1 * 32 + kc] = bl1;
        }
        __syncthreads();

        bf16x8 fah[4], fal[4];
#pragma unroll
        for (int mi = 0; mi < 4; ++mi) {
            int off = (wm * 64 + mi * 16 + l16) * 32 + quad * 8;
            fah[mi] = *(const bf16x8*)&Ah[off];
            if (threep) fal[mi] = *(const bf16x8*)&Al[off];
        }
#pragma unroll
        for (int ni = 0; ni < 4; ++ni) {
            int off = (wn * 64 + ni * 16 + l16) * 32 + quad * 8;
            bf16x8 fbh = *(const bf16x8*)&Bh[off];
            if (threep) {
                bf16x8 fbl = *(const bf16x8*)&Bl[off];
#pragma unroll
                for (int mi = 0; mi < 4; ++mi) {
                    acc[mi][ni] = __builtin_amdgcn_mfma_f32_16x16x32_bf16(fah[mi], fbh, acc[mi][ni], 0, 0, 0);
                    acc[mi][ni] = __builtin_amdgcn_mfma_f32_16x16x32_bf16(fah[mi], fbl, acc[mi][ni], 0, 0, 0);
                    acc[mi][ni] = __builtin_amdgcn_mfma_f32_16x16x32_bf16(fal[mi], fbh, acc[mi][ni], 0, 0, 0);
                }
            } else {
#pragma unroll
                for (int mi = 0; mi < 4; ++mi)
                    acc[mi][ni] = __builtin_amdgcn_mfma_f32_16x16x32_bf16(fah[mi], fbh, acc[mi][ni], 0, 0, 0);
            }
        }
    }

    // Epilogue: acc[mi][ni][r] = C[m0+wm*64+mi*16+quad*4+r][n0+wn*64+ni*16+l16]
#pragma unroll
    for (int mi = 0; mi < 4; ++mi) {
#pragma unroll
        for (int ni = 0; ni < 4; ++ni) {
            int nb = n0 + wn * 64 + ni * 16 + l16;
            int rem = nb - which * 768;
            int h = rem >> 6, d = rem & 63;
            float bv = bias[nb];
#pragma unroll
            for (int r = 0; r < 4; ++r) {
                int m = m0 + wm * 64 + mi * 16 + quad * 4 + r;
                int bb = m >> 10, s = m & 1023;
                int head = bb * 12 + h;
                float val = acc[mi][ni][r] + bv;
                if (which == 2) {
                    Vt[(size_t)head * 65536 + (size_t)d * 1024 + s] = f2bf(val);
                } else {
                    unsigned short hb = f2bf(val);
                    unsigned short lb = f2bf(val - bf2f(hb));
                    size_t idx = (size_t)head * 65536 + (size_t)s * 64 + d;
                    if (which == 0) { Qhi[idx] = hb; Qlo[idx] = lb; }
                    else            { Khi[idx] = hb; Klo[idx] = lb; }
                }
            }
        }
    }
}

// ---------------------------------------------------------------------------
// Proj GEMM via MFMA (single-pass bf16): OUT = Aob @ Wproj + b, fp32 out.
// ---------------------------------------------------------------------------
__global__ __launch_bounds__(256) void proj_mfma_kernel(
    const unsigned short* __restrict__ Ag, const unsigned short* __restrict__ Bhg,
    const float* __restrict__ bias, float* __restrict__ OUT)
{
    __shared__ unsigned short Ah[128 * 32];
    __shared__ unsigned short Bh[128 * 32];
    const int tid = threadIdx.x;
    const int n0 = blockIdx.x * 128, m0 = blockIdx.y * 128;
    const int lane = tid & 63, l16 = lane & 15, quad = lane >> 4;
    const int w = tid >> 6, wm = w >> 1, wn = w & 1;

    f32x4 acc[4][4];
#pragma unroll
    for (int mi = 0; mi < 4; ++mi)
#pragma unroll
        for (int ni = 0; ni < 4; ++ni) acc[mi][ni] = (f32x4){0.f, 0.f, 0.f, 0.f};

    const int r0 = tid >> 2, kc = (tid & 3) * 8;
    const int r1 = r0 + 64;

    for (int k0 = 0; k0 < 768; k0 += 32) {
        bf16x8 ah0 = *(const bf16x8*)&Ag[(size_t)(m0 + r0) * 768 + k0 + kc];
        bf16x8 ah1 = *(const bf16x8*)&Ag[(size_t)(m0 + r1) * 768 + k0 + kc];
        bf16x8 bh0 = *(const bf16x8*)&Bhg[(size_t)(n0 + r0) * 768 + k0 + kc];
        bf16x8 bh1 = *(const bf16x8*)&Bhg[(size_t)(n0 + r1) * 768 + k0 + kc];
        __syncthreads();
        *(bf16x8*)&Ah[r0 * 32 + kc] = ah0;
        *(bf16x8*)&Ah[r1 * 32 + kc] = ah1;
        *(bf16x8*)&Bh[r0 * 32 + kc] = bh0;
        *(bf16x8*)&Bh[r1 * 32 + kc] = bh1;
        __syncthreads();

        bf16x8 fah[4];
#pragma unroll
        for (int mi = 0; mi < 4; ++mi)
            fah[mi] = *(const bf16x8*)&Ah[(wm * 64 + mi * 16 + l16) * 32 + quad * 8];
#pragma unroll
        for (int ni = 0; ni < 4; ++ni) {
            bf16x8 fbh = *(const bf16x8*)&Bh[(wn * 64 + ni * 16 + l16) * 32 + quad * 8];
#pragma unroll
            for (int mi = 0; mi < 4; ++mi)
                acc[mi][ni] = __builtin_amdgcn_mfma_f32_16x16x32_bf16(fah[mi], fbh, acc[mi][ni], 0, 0, 0);
        }
    }

#pragma unroll
    for (int mi = 0; mi < 4; ++mi)
#pragma unroll
        for (int ni = 0; ni < 4; ++ni) {
            int nb = n0 + wn * 64 + ni * 16 + l16;
            float bv = bias[nb];
#pragma unroll
            for (int r = 0; r < 4; ++r) {
                int m = m0 + wm * 64 + mi * 16 + quad * 4 + r;
                OUT[(size_t)m * 768 + nb] = acc[mi][ni][r] + bv;
            }
        }
}

// ---------------------------------------------------------------------------
// Attention (R2-proven, verbatim) — only the final store now emits bf16 Aob.
// ---------------------------------------------------------------------------
__global__ __launch_bounds__(256) void attn_kernel(
    const unsigned short* __restrict__ Qhi, const unsigned short* __restrict__ Qlo,
    const unsigned short* __restrict__ Khi, const unsigned short* __restrict__ Klo,
    const unsigned short* __restrict__ Vt, unsigned short* __restrict__ Aob)
{
    __shared__ float S[16 * 1024];   // 64 KB: scores -> P -> partials(+rsum)

    const int head = blockIdx.y;
    const int qt = blockIdx.x;       // 16-row q tile
    const int bb = head / 12, h = head - bb * 12;
    const int tid = threadIdx.x;
    const int w = tid >> 6, lane = tid & 63;
    const int l16 = lane & 15, quad = lane >> 4;

    const size_t hbase = (size_t)head * 65536;
    const unsigned short* Qhp = Qhi + hbase + (size_t)(qt * 16) * 64;
    const unsigned short* Qlp = Qlo + hbase + (size_t)(qt * 16) * 64;
    const unsigned short* Khp = Khi + hbase;
    const unsigned short* Klp = Klo + hbase;
    const unsigned short* Vp  = Vt + hbase;   // [64][1024]

    bf16x8 qh0, qh1, ql0, ql1;
    {
        int off = l16 * 64 + quad * 8;
        qh0 = *(const bf16x8*)(Qhp + off);
        qh1 = *(const bf16x8*)(Qhp + off + 32);
        ql0 = *(const bf16x8*)(Qlp + off);
        ql1 = *(const bf16x8*)(Qlp + off + 32);
    }

    // ---- Phase 1: scores for cols [w*256, w*256+256) ----
    for (int t = 0; t < 16; ++t) {
        int col0 = w * 256 + t * 16;
        int off = (col0 + l16) * 64 + quad * 8;
        bf16x8 kh0 = *(const bf16x8*)(Khp + off);
        bf16x8 kh1 = *(const bf16x8*)(Khp + off + 32);
        bf16x8 kl0 = *(const bf16x8*)(Klp + off);
        bf16x8 kl1 = *(const bf16x8*)(Klp + off + 32);
        f32x4 acc = {0.f, 0.f, 0.f, 0.f};
        acc = __builtin_amdgcn_mfma_f32_16x16x32_bf16(qh0, kh0, acc, 0, 0, 0);
        acc = __builtin_amdgcn_mfma_f32_16x16x32_bf16(qh1, kh1, acc, 0, 0, 0);
        acc = __builtin_amdgcn_mfma_f32_16x16x32_bf16(qh0, kl0, acc, 0, 0, 0);
        acc = __builtin_amdgcn_mfma_f32_16x16x32_bf16(qh1, kl1, acc, 0, 0, 0);
        acc = __builtin_amdgcn_mfma_f32_16x16x32_bf16(ql0, kh0, acc, 0, 0, 0);
        acc = __builtin_amdgcn_mfma_f32_16x16x32_bf16(ql1, kh1, acc, 0, 0, 0);
#pragma unroll
        for (int r = 0; r < 4; ++r)
            S[(quad * 4 + r) * 1024 + col0 + l16] = acc[r] * 0.125f;
    }
    __syncthreads();

    // ---- Phase 2: row r2 handled by 16-lane group; 64 values/lane ----
    const int r2 = w * 4 + quad;
    float* Srow = &S[r2 * 1024];
    unsigned ua[64];
    float m = -1e30f;
#pragma unroll
    for (int i = 0; i < 16; ++i) {
        f32x4 v = *(const f32x4*)&Srow[l16 * 4 + i * 64];
#pragma unroll
        for (int k = 0; k < 4; ++k) {
            float f = v[k];
            m = fmaxf(m, f);
            unsigned u = __float_as_uint(f);
            ua[i * 4 + k] = (u & 0x80000000u) ? ~u : (u | 0x80000000u);
        }
    }
#pragma unroll
    for (int off = 8; off; off >>= 1) m = fmaxf(m, __shfl_xor(m, off));

    unsigned ans = 0u;
    for (int bit = 31; bit >= 0; --bit) {
        unsigned c = ans | (1u << bit);
        int cnt = 0;
#pragma unroll
        for (int i = 0; i < 64; ++i) cnt += (ua[i] >= c) ? 1 : 0;
        cnt += __shfl_xor(cnt, 1);
        cnt += __shfl_xor(cnt, 2);
        cnt += __shfl_xor(cnt, 4);
        cnt += __shfl_xor(cnt, 8);
        if (cnt >= TOPK) ans = c;
    }

    float ssum = 0.f;
#pragma unroll
    for (int i = 0; i < 64; ++i) {
        unsigned u = ua[i];
        unsigned fb = (u & 0x80000000u) ? (u & 0x7fffffffu) : ~u;
        float f = __uint_as_float(fb);
        float e = (u >= ans) ? exp2f((f - m) * LOG2E) : 0.f;
        ssum += e;
        Srow[l16 * 4 + (i >> 2) * 64 + (i & 3)] = e;
    }
#pragma unroll
    for (int off = 8; off; off >>= 1) ssum += __shfl_xor(ssum, off);
    const float rsum = ssum;
    __syncthreads();

    // ---- Phase 3: partial O over k in [w*256, w*256+256) ----
    f32x4 oacc[4];
#pragma unroll
    for (int nt = 0; nt < 4; ++nt) oacc[nt] = (f32x4){0.f, 0.f, 0.f, 0.f};

    for (int step = 0; step < 8; ++step) {
        int k0 = w * 256 + step * 32;
        f32x4 p0 = *(const f32x4*)&S[l16 * 1024 + k0 + quad * 8];
        f32x4 p1 = *(const f32x4*)&S[l16 * 1024 + k0 + quad * 8 + 4];
        bf16x8 a;
#pragma unroll
        for (int k = 0; k < 4; ++k) a[k] = (short)f2bf(p0[k]);
#pragma unroll
        for (int k = 0; k < 4; ++k) a[4 + k] = (short)f2bf(p1[k]);
#pragma unroll
        for (int nt = 0; nt < 4; ++nt) {
            bf16x8 bfrag = *(const bf16x8*)(Vp + (size_t)(nt * 16 + l16) * 1024 + k0 + quad * 8);
            oacc[nt] = __builtin_amdgcn_mfma_f32_16x16x32_bf16(a, bfrag, oacc[nt], 0, 0, 0);
        }
    }
    __syncthreads();   // all P reads done; S reusable

    // partials: S[(w*16 + row)*64 + col], rsum at S[4096 + r]
#pragma unroll
    for (int nt = 0; nt < 4; ++nt)
#pragma unroll
        for (int r = 0; r < 4; ++r)
            S[(w * 16 + quad * 4 + r) * 64 + nt * 16 + l16] = oacc[nt][r];
    if (l16 == 0) S[4096 + r2] = rsum;
    __syncthreads();

    {
        int row = tid >> 4, ds = (tid & 15) * 4;
        f32x4 o = {0.f, 0.f, 0.f, 0.f};
#pragma unroll
        for (int ww = 0; ww < 4; ++ww)
            o += *(const f32x4*)&S[(ww * 16 + row) * 64 + ds];
        float inv = 1.f / S[4096 + row];
        int srow = qt * 16 + row;
        us4 res;
#pragma unroll
        for (int k = 0; k < 4; ++k) res[k] = f2bf(o[k] * inv);
        *(us4*)&Aob[((size_t)(bb * 1024 + srow)) * 768 + h * 64 + ds] = res;
    }
}

extern "C" void kernel_launch(void* const* d_in, const int* in_sizes, int n_in,
                              void* d_out, int out_size, void* d_ws, size_t ws_size,
                              hipStream_t stream)
{
    const float* X     = (const float*)d_in[0];
    const float* Wqkv  = (const float*)d_in[1];
    const float* bqkv  = (const float*)d_in[2];
    const float* Wproj = (const float*)d_in[3];
    const float* bproj = (const float*)d_in[4];
    float* out = (float*)d_out;

    unsigned short* us = (unsigned short*)d_ws;
    const size_t P = (size_t)8192 * 768;          // 6291456
    unsigned short* Xhi = us;
    unsigned short* Xlo = Xhi + P;
    unsigned short* Wqh = Xlo + P;                // [2304][768]
    unsigned short* Wql = Wqh + (size_t)2304 * 768;
    unsigned short* Wph = Wql + (size_t)2304 * 768;  // [768][768]
    unsigned short* Wpl = Wph + (size_t)768 * 768;
    unsigned short* Qhi = Wpl + (size_t)768 * 768;
    unsigned short* Qlo = Qhi + P;
    unsigned short* Khi = Qlo + P;
    unsigned short* Klo = Khi + P;
    unsigned short* Vt  = Klo + P;
    unsigned short* Aob = Xhi;   // reuse: X consumed by qkv before attn writes Aob

    cast_x_kernel<<<3072, 256, 0, stream>>>(X, Xhi, Xlo);
    transpose_split_kernel<<<dim3(72, 24), 256, 0, stream>>>(Wqkv, Wqh, Wql, 768, 2304);
    transpose_split_kernel<<<dim3(24, 24), 256, 0, stream>>>(Wproj, Wph, Wpl, 768, 768);
    qkv_mfma_kernel<<<dim3(18, 64), 256, 0, stream>>>(Xhi, Xlo, Wqh, Wql, bqkv,
                                                      Qhi, Qlo, Khi, Klo, Vt);
    attn_kernel<<<dim3(64, 96), 256, 0, stream>>>(Qhi, Qlo, Khi, Klo, Vt, Aob);
    proj_mfma_kernel<<<dim3(6, 64), 256, 0, stream>>>(Aob, Wph, bproj, out);
}